// Round 13
// baseline (683.309 us; speedup 1.0000x reference)
//
#include <hip/hip_runtime.h>

#define NTHREADS 256
#define HID 96
#define INF 64
#define OUTF 16
#define NLAYERS 16
#define NHW 25088     // packed histogram words (2 nodes/word), fits n<=50176
#define CB 128        // histogram/scatter blocks (per-block edges 6250 < 65536)

typedef __attribute__((ext_vector_type(8))) unsigned short ushort8_t;
typedef __attribute__((ext_vector_type(8))) short short8_t;   // MFMA bf16 A/B frag
typedef __attribute__((ext_vector_type(4))) float f32x4_t;    // MFMA C/D frag

static __device__ __forceinline__ float bf2f(unsigned short u) {
  return __uint_as_float(((unsigned)u) << 16);
}
static __device__ __forceinline__ unsigned short f2bf(float x) {
  unsigned u = __float_as_uint(x);
  return (unsigned short)((u + 0x7FFF + ((u >> 16) & 1)) >> 16);  // RNE
}
static __device__ __forceinline__ unsigned pack2bf(float a, float b) {
  return (unsigned)f2bf(a) | ((unsigned)f2bf(b) << 16);
}

// ---------------- preprocessing ----------------
// LDS-privatized histogram over idx[] (row or col), packed 2 nodes/u32 word.
__global__ __launch_bounds__(NTHREADS) void k_hist(
    const int* __restrict__ idx, int e, unsigned* __restrict__ part, int nw) {
  __shared__ unsigned hh[NHW];
  int tid = threadIdx.x;
  for (int i = tid; i < NHW; i += NTHREADS) hh[i] = 0;
  __syncthreads();
  int per = (e + CB - 1) / CB;
  int s = blockIdx.x * per;
  int en = min(e, s + per);
  for (int i = s + tid; i < en; i += NTHREADS) {
    int v = idx[i];
    atomicAdd(&hh[v >> 1], (v & 1) ? 0x10000u : 1u);
  }
  __syncthreads();
  unsigned* dst = part + (size_t)blockIdx.x * NHW;
  for (int i = tid; i < nw; i += NTHREADS) dst[i] = hh[i];
}

// Sum the CB partial histograms -> cnt (rows); degree over cols -> dis/rdis.
// Also rewrites partR in place as the EXCLUSIVE PREFIX over blocks (packed u16).
__global__ void k_hmerge(unsigned* __restrict__ partR,
                         const unsigned* __restrict__ partC,
                         int* __restrict__ cnt, float* __restrict__ dis,
                         float* __restrict__ rdis, int n, int nw) {
  int w = blockIdx.x * NTHREADS + threadIdx.x;
  if (w >= nw) return;
  unsigned rl = 0, rh = 0, cl = 0, ch = 0;
#pragma unroll 4
  for (int b = 0; b < CB; ++b) {
    size_t o = (size_t)b * NHW + w;
    unsigned pr = partR[o];
    partR[o] = rl | (rh << 16);          // exclusive prefix (fits u16)
    rl += pr & 0xFFFFu; rh += pr >> 16;
    unsigned pc = partC[o];
    cl += pc & 0xFFFFu; ch += pc >> 16;
  }
  int i0 = 2 * w, i1 = 2 * w + 1;
  if (i0 < n) {
    cnt[i0] = 1 + (int)rl;
    float d = (float)(1 + (int)cl);
    dis[i0] = rsqrtf(d); rdis[i0] = sqrtf(d);
  }
  if (i1 < n) {
    cnt[i1] = 1 + (int)rh;
    float d = (float)(1 + (int)ch);
    dis[i1] = rsqrtf(d); rdis[i1] = sqrtf(d);
  }
}

__global__ void k_scan1(const int* __restrict__ cnt, int* __restrict__ rp,
                        int* __restrict__ bsum, int n) {
  __shared__ int sh[NTHREADS];
  int t = threadIdx.x;
  int i = blockIdx.x * NTHREADS + t;
  int v = (i < n) ? cnt[i] : 0;
  sh[t] = v;
  __syncthreads();
  for (int ofs = 1; ofs < NTHREADS; ofs <<= 1) {
    int u = (t >= ofs) ? sh[t - ofs] : 0;
    __syncthreads();
    sh[t] += u;
    __syncthreads();
  }
  if (i < n) rp[i] = sh[t] - v;
  if (t == NTHREADS - 1) bsum[blockIdx.x] = sh[t];
}

__global__ void k_scan2(int* __restrict__ bsum, int nb) {  // nb <= 256
  __shared__ int sh[NTHREADS];
  int t = threadIdx.x;
  int v = (t < nb) ? bsum[t] : 0;
  sh[t] = v;
  __syncthreads();
  for (int ofs = 1; ofs < NTHREADS; ofs <<= 1) {
    int u = (t >= ofs) ? sh[t - ofs] : 0;
    __syncthreads();
    sh[t] += u;
    __syncthreads();
  }
  if (t < nb) bsum[t] = sh[t] - v;
}

// finalize rp AND write the self-loop edge into slot 0 of each row
__global__ void k_scan3(int* __restrict__ rp, const int* __restrict__ bsum,
                        int* __restrict__ ev, int n, int etot) {
  int i = blockIdx.x * NTHREADS + threadIdx.x;
  if (i < n) {
    int v = rp[i] + bsum[blockIdx.x];
    rp[i] = v;
    ev[v] = i;                 // self-loop: gathers hs[i] = dis[i]*h[i]
  }
  if (i == 0) rp[n] = etot;
}

// Atomic-free-global scatter (cols only; no val):
// slot = rp[r] + 1 (self slot) + prefix_over_blocks[b][r] + LDS-local counter.
__global__ __launch_bounds__(NTHREADS) void k_scatter3(
    const int* __restrict__ row, const int* __restrict__ col,
    const int* __restrict__ rp, const unsigned* __restrict__ prefR,
    int* __restrict__ ev, int e) {
  __shared__ unsigned lcur[NHW];
  int tid = threadIdx.x;
  for (int i = tid; i < NHW; i += NTHREADS) lcur[i] = 0;
  __syncthreads();
  int per = (e + CB - 1) / CB;
  int s = blockIdx.x * per;
  int en = min(e, s + per);
  const unsigned* pref = prefR + (size_t)blockIdx.x * NHW;
  for (int i = s + tid; i < en; i += NTHREADS) {
    int r = row[i], c = col[i];
    unsigned old = atomicAdd(&lcur[r >> 1], (r & 1) ? 0x10000u : 1u);
    unsigned loc = (r & 1) ? (old >> 16) : (old & 0xFFFFu);
    unsigned pw = pref[r >> 1];
    unsigned pb = (r & 1) ? (pw >> 16) : (pw & 0xFFFFu);
    ev[rp[r] + 1 + (int)pb + (int)loc] = c;
  }
}

// wT_bf16[l][f][k] = bf16(conv_w[l][k][f])  (transposed for MFMA B-fragments)
__global__ void k_wprime(const float* __restrict__ cw,
                         unsigned short* __restrict__ wTb) {
  int l = blockIdx.y;
  int idx = blockIdx.x * NTHREADS + threadIdx.x;   // 0..9215 = f*96 + k
  int f = idx / HID, k = idx % HID;
  wTb[l * HID * HID + idx] = f2bf(cw[l * HID * HID + k * HID + f]);
}

// ------ h0 = relu(x @ w0^T + b0): x0b = bf16(h0), hs0 = bf16(dis*h0) ---------
__global__ __launch_bounds__(NTHREADS) void k_lin0(
    const float* __restrict__ x, const float* __restrict__ w0,
    const float* __restrict__ b0, const float* __restrict__ dis,
    unsigned short* __restrict__ x0b, unsigned short* __restrict__ hs0, int n) {
  __shared__ float wl[INF * HID];   // wl[c][h], stride 96
  __shared__ float xT[INF * 68];    // xT[c][r], padded stride 68
  int tid = threadIdx.x;
#pragma unroll
  for (int i = 0; i < 6; ++i) {     // w0: 96x64 = 1536 float4
    int idx = tid + i * NTHREADS;
    int hrow = idx / 16, q = idx % 16;
    float4 v = *(const float4*)(w0 + hrow * INF + q * 4);
    wl[(q * 4 + 0) * HID + hrow] = v.x;
    wl[(q * 4 + 1) * HID + hrow] = v.y;
    wl[(q * 4 + 2) * HID + hrow] = v.z;
    wl[(q * 4 + 3) * HID + hrow] = v.w;
  }
  int r0 = blockIdx.x * 64;
#pragma unroll
  for (int i = 0; i < 4; ++i) {     // x tile: 64x64 = 1024 float4
    int idx = tid + i * NTHREADS;
    int r = idx / 16, q = idx % 16;
    int gr = r0 + r;
    float4 v = make_float4(0.f, 0.f, 0.f, 0.f);
    if (gr < n) v = *(const float4*)(x + (size_t)gr * INF + q * 4);
    xT[(q * 4 + 0) * 68 + r] = v.x;
    xT[(q * 4 + 1) * 68 + r] = v.y;
    xT[(q * 4 + 2) * 68 + r] = v.z;
    xT[(q * 4 + 3) * 68 + r] = v.w;
  }
  __syncthreads();
  int rg = tid & 15, cg = tid >> 4;
  float acc[4][6];
#pragma unroll
  for (int i = 0; i < 4; ++i)
#pragma unroll
    for (int j = 0; j < 6; ++j) acc[i][j] = 0.f;
#pragma unroll 4
  for (int k = 0; k < INF; ++k) {
    float4 s4 = *(const float4*)(xT + k * 68 + rg * 4);
    const float2* w2 = (const float2*)(wl + k * HID + cg * 6);
    float2 wa = w2[0], wb = w2[1], wc = w2[2];
    float wv[6] = {wa.x, wa.y, wb.x, wb.y, wc.x, wc.y};
    float sv[4] = {s4.x, s4.y, s4.z, s4.w};
#pragma unroll
    for (int i = 0; i < 4; ++i)
#pragma unroll
      for (int j = 0; j < 6; ++j) acc[i][j] = fmaf(sv[i], wv[j], acc[i][j]);
  }
  float bb[6];
#pragma unroll
  for (int j = 0; j < 6; ++j) bb[j] = b0[cg * 6 + j];
#pragma unroll
  for (int i = 0; i < 4; ++i) {
    int gr = r0 + rg * 4 + i;
    if (gr < n) {
      float r_[6];
#pragma unroll
      for (int j = 0; j < 6; ++j) r_[j] = fmaxf(acc[i][j] + bb[j], 0.f);
      float dr = dis[gr];
      unsigned* ob = (unsigned*)(x0b + (size_t)gr * HID + cg * 6);
      ob[0] = pack2bf(r_[0], r_[1]);
      ob[1] = pack2bf(r_[2], r_[3]);
      ob[2] = pack2bf(r_[4], r_[5]);
      unsigned* oh = (unsigned*)(hs0 + (size_t)gr * HID + cg * 6);
      oh[0] = pack2bf(dr * r_[0], dr * r_[1]);
      oh[1] = pack2bf(dr * r_[2], dr * r_[3]);
      oh[2] = pack2bf(dr * r_[4], dr * r_[5]);
    }
  }
}

// ---- fused layer: hs' = dis * relu((1-b)*s + b*(s @ w)),
//      s = 0.9*dis[r]*Σ hs[c] + 0.1*x0.
// 24 rows/block (grid 2084): LDS 19.5 KB -> 8 blocks/CU resident = 32 waves/CU
// (HW max; R12's 32-row grid supplied only ~6 blocks = 24 waves).
// Phase 1: 8 half-waves x 3 subs; one shfl_xor step + LDS reduce over 4 slots.
// Phase 2: sT padded to 32 rows; 12 MFMA tiles / 4 waves = 3 each; rows 24-31
// are uninitialized garbage whose outputs are discarded (rl<24 guard — C rows
// depend only on A rows). B from global wT (L2-resident).
__global__ __launch_bounds__(NTHREADS, 4) void k_layer(
    const unsigned short* __restrict__ hs, const unsigned short* __restrict__ x0,
    const float* __restrict__ dis, const int* __restrict__ rp,
    const int* __restrict__ ev, const unsigned short* __restrict__ wT,
    unsigned short* __restrict__ hsout, float omb, float beta, int n) {
  __shared__ float red[8][4][100];          // 12.8 KB
  __shared__ unsigned short sT[32 * 104];   // 6.7 KB (rows 24-31 pad)
  int tid = threadIdx.x;
  int hw = tid >> 5, lane = tid & 31;
  int eb = lane >> 2, fg = lane & 3;
  int r0 = blockIdx.x * 24;

  // ---- phase 1: SpMM + residual into sT (rows 0..23) ----
  for (int sub = 0; sub < 3; ++sub) {
    int rl = sub * 8 + hw;
    int r = r0 + rl;
    if (r >= n) r = n - 1;          // duplicate work; store guarded in phase 2
    int e0 = rp[r], e1 = rp[r + 1]; // >= 1 edge (self-loop)
    float acc[24];
#pragma unroll
    for (int j = 0; j < 24; ++j) acc[j] = 0.f;
    int idx0 = e0 + eb;
    bool ok = idx0 < e1;
    idx0 = ok ? idx0 : e1 - 1;
    int cv = ev[idx0];
    for (int base = e0; base < e1; base += 8) {
      int cur = cv;
      bool okc = ok;
      int nb = base + 8;
      if (nb < e1) {                // prefetch next batch
        int i2 = nb + eb;
        ok = i2 < e1;
        i2 = ok ? i2 : e1 - 1;
        cv = ev[i2];
      }
      float v = okc ? 1.f : 0.f;    // lane mask (edge weight folded into hs)
      const unsigned short* hc = hs + (size_t)cur * HID + fg * 24;
      ushort8_t p0 = *(const ushort8_t*)(hc);
      ushort8_t p1 = *(const ushort8_t*)(hc + 8);
      ushort8_t p2 = *(const ushort8_t*)(hc + 16);
#pragma unroll
      for (int j = 0; j < 8; ++j) acc[j]      = fmaf(v, bf2f(p0[j]), acc[j]);
#pragma unroll
      for (int j = 0; j < 8; ++j) acc[8 + j]  = fmaf(v, bf2f(p1[j]), acc[8 + j]);
#pragma unroll
      for (int j = 0; j < 8; ++j) acc[16 + j] = fmaf(v, bf2f(p2[j]), acc[16 + j]);
    }
    // one butterfly step: pair edge-slots (eb, eb^1)
#pragma unroll
    for (int j = 0; j < 24; ++j) acc[j] += __shfl_xor(acc[j], 4);
    if ((eb & 1) == 0) {            // even-eb lanes hold pair sums -> 4 slots
      float* myr = &red[hw][eb >> 1][fg * 24];
#pragma unroll
      for (int j = 0; j < 6; ++j)
        *(float4*)(myr + j * 4) =
            make_float4(acc[j * 4], acc[j * 4 + 1], acc[j * 4 + 2], acc[j * 4 + 3]);
    }
    asm volatile("s_waitcnt lgkmcnt(0)" ::: "memory");
    __builtin_amdgcn_wave_barrier();
    if (lane < 24) {
      const float* base = &red[hw][0][lane * 4];
      float4 tot = *(const float4*)(base);
#pragma unroll
      for (int b = 1; b < 4; ++b) {
        float4 p = *(const float4*)(base + b * 100);
        tot.x += p.x; tot.y += p.y; tot.z += p.z; tot.w += p.w;
      }
      float w09 = 0.9f * dis[r];
      const unsigned* xr = (const unsigned*)(x0 + (size_t)r * HID + lane * 4);
      unsigned xa = xr[0], xb = xr[1];
      float s0 = w09 * tot.x + 0.1f * bf2f((unsigned short)(xa & 0xFFFFu));
      float s1 = w09 * tot.y + 0.1f * bf2f((unsigned short)(xa >> 16));
      float s2 = w09 * tot.z + 0.1f * bf2f((unsigned short)(xb & 0xFFFFu));
      float s3 = w09 * tot.w + 0.1f * bf2f((unsigned short)(xb >> 16));
      unsigned* op = (unsigned*)(sT + rl * 104 + lane * 4);
      op[0] = pack2bf(s0, s1);
      op[1] = pack2bf(s2, s3);
    }
    asm volatile("" ::: "memory");
    __builtin_amdgcn_wave_barrier();  // red reads done before next sub's writes
  }
  __syncthreads();
  // ---- phase 2: MFMA gemm; 4 waves x 3 tiles (2 rowblocks x 6 colblocks) ----
  int lane64 = tid & 63, wave = tid >> 6;
  int l15 = lane64 & 15;    // A-row / B-col / C-col
  int kg = lane64 >> 4;     // k-group 0..3
  int rb = (wave & 1) * 16; // row block (16-31 mostly pad)
  int cb = (wave >> 1) * 48; // col block
  f32x4_t acc2[3];
#pragma unroll
  for (int i = 0; i < 3; ++i) acc2[i] = (f32x4_t)(0.f);
#pragma unroll
  for (int kt = 0; kt < 3; ++kt) {
    short8_t A = *(const short8_t*)(sT + (rb + l15) * 104 + kt * 32 + kg * 8);
#pragma unroll
    for (int ft = 0; ft < 3; ++ft) {
      short8_t B = *(const short8_t*)(wT + (cb + ft * 16 + l15) * HID + kt * 32 + kg * 8);
      acc2[ft] = __builtin_amdgcn_mfma_f32_16x16x32_bf16(A, B, acc2[ft], 0, 0, 0);
    }
  }
  // epilogue: C layout col = lane&15, row = (lane>>4)*4 + j   [m89-verified]
#pragma unroll
  for (int ft = 0; ft < 3; ++ft) {
    int col = cb + ft * 16 + l15;
#pragma unroll
    for (int j = 0; j < 4; ++j) {
      int rl = rb + kg * 4 + j;
      int gr = r0 + rl;
      if (rl < 24 && gr < n) {
        float sv = bf2f(sT[rl * 104 + col]);
        float o = fmaxf(omb * sv + beta * acc2[ft][j], 0.f);
        hsout[(size_t)gr * HID + col] = f2bf(dis[gr] * o);
      }
    }
  }
}

// ------------- out = h @ w1^T + b1, h = rdis * hs (unscale on load) -----------
__global__ __launch_bounds__(NTHREADS) void k_lin1(
    const unsigned short* __restrict__ hs, const float* __restrict__ rdis,
    const float* __restrict__ w1, const float* __restrict__ b1,
    float* __restrict__ out, int n) {
  __shared__ float hT[HID * 68];    // [k][r]
  __shared__ float w1l[HID * OUTF]; // [k][o]
  int tid = threadIdx.x;
#pragma unroll
  for (int i = 0; i < 6; ++i) {     // w1: 16x96 = 1536 floats
    int idx = tid + i * NTHREADS;
    int o = idx / HID, k = idx % HID;
    w1l[k * OUTF + o] = w1[idx];
  }
  int r0 = blockIdx.x * 64;
#pragma unroll
  for (int i = 0; i < 3; ++i) {     // hs tile: 64x96 bf16 = 768 ushort8
    int idx = tid + i * NTHREADS;
    int r = idx / 12, q = idx % 12;
    int gr = r0 + r;
    ushort8_t v = (ushort8_t)0;
    float sc = 0.f;
    if (gr < n) {
      v = *(const ushort8_t*)(hs + (size_t)gr * HID + q * 8);
      sc = rdis[gr];
    }
#pragma unroll
    for (int j = 0; j < 8; ++j) hT[(q * 8 + j) * 68 + r] = sc * bf2f(v[j]);
  }
  __syncthreads();
  int r = tid & 63, og = tid >> 6;
  float acc[4] = {0.f, 0.f, 0.f, 0.f};
#pragma unroll 4
  for (int k = 0; k < HID; ++k) {
    float s = hT[k * 68 + r];
    float4 w4 = *(const float4*)(w1l + k * OUTF + og * 4);
    acc[0] = fmaf(s, w4.x, acc[0]);
    acc[1] = fmaf(s, w4.y, acc[1]);
    acc[2] = fmaf(s, w4.z, acc[2]);
    acc[3] = fmaf(s, w4.w, acc[3]);
  }
  int gr = r0 + r;
  if (gr < n) {
    float* op = out + (size_t)gr * OUTF + og * 4;
#pragma unroll
    for (int j = 0; j < 4; ++j) op[j] = acc[j] + b1[og * 4 + j];
  }
}

extern "C" void kernel_launch(void* const* d_in, const int* in_sizes, int n_in,
                              void* d_out, int out_size, void* d_ws, size_t ws_size,
                              hipStream_t stream) {
  const float* x  = (const float*)d_in[0];
  const int*   ei = (const int*)d_in[1];     // [2][E]: rows then cols
  const float* w0 = (const float*)d_in[2];
  const float* b0 = (const float*)d_in[3];
  const float* w1 = (const float*)d_in[4];
  const float* b1 = (const float*)d_in[5];
  const float* cw = (const float*)d_in[6];
  int n = in_sizes[0] / INF;    // 50000
  int e = in_sizes[1] / 2;      // 800000
  const int* row = ei;
  const int* col = ei + e;

  char* ws = (char*)d_ws;
  size_t off = 0;
  auto alloc = [&](size_t bytes) -> void* {
    void* p = (void*)(ws + off);
    off += (bytes + 255) & ~(size_t)255;
    return p;
  };
  unsigned short* x0b = (unsigned short*)alloc((size_t)n * HID * 2);
  unsigned short* hsA = (unsigned short*)alloc((size_t)n * HID * 2);
  unsigned short* hsB = (unsigned short*)alloc((size_t)n * HID * 2);
  unsigned short* wTb = (unsigned short*)alloc((size_t)NLAYERS * HID * HID * 2);
  float* dis  = (float*)alloc((size_t)n * 4);
  float* rdis = (float*)alloc((size_t)n * 4);
  int*   cnt  = (int*)alloc((size_t)n * 4);
  int*   rp   = (int*)alloc((size_t)(n + 1) * 4);
  int*   ev   = (int*)alloc((size_t)(e + n) * 4);   // + self-loop slots
  int*   bsum = (int*)alloc(1024 * 4);
  // partial histograms alias x0b/hsA/hsB (25.7 MB <= 28.8 MB; those buffers are
  // first written by k_lin0 / k_layer, which run after k_scatter3)
  unsigned* partR = (unsigned*)x0b;
  unsigned* partC = partR + (size_t)CB * NHW;
  int nw = (n + 1) / 2;         // packed words (<= NHW)
  (void)ws_size; (void)n_in; (void)out_size;

  int nb  = (n + NTHREADS - 1) / NTHREADS;   // 196
  int r64 = (n + 63) / 64;                   // 782
  int r24 = (n + 23) / 24;                   // 2084

  k_hist<<<CB, NTHREADS, 0, stream>>>(row, e, partR, nw);
  k_hist<<<CB, NTHREADS, 0, stream>>>(col, e, partC, nw);
  k_hmerge<<<(nw + NTHREADS - 1) / NTHREADS, NTHREADS, 0, stream>>>(
      partR, partC, cnt, dis, rdis, n, nw);
  k_scan1<<<nb, NTHREADS, 0, stream>>>(cnt, rp, bsum, n);
  k_scan2<<<1, NTHREADS, 0, stream>>>(bsum, nb);
  k_scan3<<<nb, NTHREADS, 0, stream>>>(rp, bsum, ev, n, e + n);
  k_scatter3<<<CB, NTHREADS, 0, stream>>>(row, col, rp, partR, ev, e);
  k_wprime<<<dim3(36, NLAYERS), NTHREADS, 0, stream>>>(cw, wTb);
  k_lin0<<<r64, NTHREADS, 0, stream>>>(x, w0, b0, dis, x0b, hsA, n);

  const unsigned short* hin = hsA;
  for (int l = 0; l < NLAYERS; ++l) {
    unsigned short* hout = (l & 1) ? hsA : hsB;
    float beta = logf(0.5f / (float)(l + 1) + 1.0f);
    k_layer<<<r24, NTHREADS, 0, stream>>>(hin, x0b, dis, rp, ev,
                                          wTb + (size_t)l * HID * HID, hout,
                                          1.0f - beta, beta, n);
    hin = hout;
  }
  k_lin1<<<r64, NTHREADS, 0, stream>>>(hin, rdis, w1, b1, (float*)d_out, n);
}

// Round 15
// 682.549 us; speedup vs baseline: 1.0011x; 1.0011x over previous
//
#include <hip/hip_runtime.h>

#define NTHREADS 256
#define HID 96
#define INF 64
#define OUTF 16
#define NLAYERS 16
#define NHW 25088     // packed histogram words (2 nodes/word), fits n<=50176
#define CB 128        // histogram/scatter blocks (per-block edges 6250 < 65536)

typedef __attribute__((ext_vector_type(8))) unsigned short ushort8_t;
typedef __attribute__((ext_vector_type(8))) short short8_t;   // MFMA bf16 A/B frag
typedef __attribute__((ext_vector_type(4))) float f32x4_t;    // MFMA C/D frag

static __device__ __forceinline__ float bf2f(unsigned short u) {
  return __uint_as_float(((unsigned)u) << 16);
}
static __device__ __forceinline__ unsigned short f2bf(float x) {
  unsigned u = __float_as_uint(x);
  return (unsigned short)((u + 0x7FFF + ((u >> 16) & 1)) >> 16);  // RNE
}
static __device__ __forceinline__ unsigned pack2bf(float a, float b) {
  return (unsigned)f2bf(a) | ((unsigned)f2bf(b) << 16);
}

// ---------------- preprocessing ----------------
// LDS-privatized histogram over idx[] (row or col), packed 2 nodes/u32 word.
__global__ __launch_bounds__(NTHREADS) void k_hist(
    const int* __restrict__ idx, int e, unsigned* __restrict__ part, int nw) {
  __shared__ unsigned hh[NHW];
  int tid = threadIdx.x;
  for (int i = tid; i < NHW; i += NTHREADS) hh[i] = 0;
  __syncthreads();
  int per = (e + CB - 1) / CB;
  int s = blockIdx.x * per;
  int en = min(e, s + per);
  for (int i = s + tid; i < en; i += NTHREADS) {
    int v = idx[i];
    atomicAdd(&hh[v >> 1], (v & 1) ? 0x10000u : 1u);
  }
  __syncthreads();
  unsigned* dst = part + (size_t)blockIdx.x * NHW;
  for (int i = tid; i < nw; i += NTHREADS) dst[i] = hh[i];
}

// Sum the CB partial histograms -> cnt (rows); degree over cols -> dis/rdis.
// Also rewrites partR in place as the EXCLUSIVE PREFIX over blocks (packed u16).
__global__ void k_hmerge(unsigned* __restrict__ partR,
                         const unsigned* __restrict__ partC,
                         int* __restrict__ cnt, float* __restrict__ dis,
                         float* __restrict__ rdis, int n, int nw) {
  int w = blockIdx.x * NTHREADS + threadIdx.x;
  if (w >= nw) return;
  unsigned rl = 0, rh = 0, cl = 0, ch = 0;
#pragma unroll 4
  for (int b = 0; b < CB; ++b) {
    size_t o = (size_t)b * NHW + w;
    unsigned pr = partR[o];
    partR[o] = rl | (rh << 16);          // exclusive prefix (fits u16)
    rl += pr & 0xFFFFu; rh += pr >> 16;
    unsigned pc = partC[o];
    cl += pc & 0xFFFFu; ch += pc >> 16;
  }
  int i0 = 2 * w, i1 = 2 * w + 1;
  if (i0 < n) {
    cnt[i0] = 1 + (int)rl;
    float d = (float)(1 + (int)cl);
    dis[i0] = rsqrtf(d); rdis[i0] = sqrtf(d);
  }
  if (i1 < n) {
    cnt[i1] = 1 + (int)rh;
    float d = (float)(1 + (int)ch);
    dis[i1] = rsqrtf(d); rdis[i1] = sqrtf(d);
  }
}

__global__ void k_scan1(const int* __restrict__ cnt, int* __restrict__ rp,
                        int* __restrict__ bsum, int n) {
  __shared__ int sh[NTHREADS];
  int t = threadIdx.x;
  int i = blockIdx.x * NTHREADS + t;
  int v = (i < n) ? cnt[i] : 0;
  sh[t] = v;
  __syncthreads();
  for (int ofs = 1; ofs < NTHREADS; ofs <<= 1) {
    int u = (t >= ofs) ? sh[t - ofs] : 0;
    __syncthreads();
    sh[t] += u;
    __syncthreads();
  }
  if (i < n) rp[i] = sh[t] - v;
  if (t == NTHREADS - 1) bsum[blockIdx.x] = sh[t];
}

__global__ void k_scan2(int* __restrict__ bsum, int nb) {  // nb <= 256
  __shared__ int sh[NTHREADS];
  int t = threadIdx.x;
  int v = (t < nb) ? bsum[t] : 0;
  sh[t] = v;
  __syncthreads();
  for (int ofs = 1; ofs < NTHREADS; ofs <<= 1) {
    int u = (t >= ofs) ? sh[t - ofs] : 0;
    __syncthreads();
    sh[t] += u;
    __syncthreads();
  }
  if (t < nb) bsum[t] = sh[t] - v;
}

// finalize rp AND write the self-loop edge into slot 0 of each row
__global__ void k_scan3(int* __restrict__ rp, const int* __restrict__ bsum,
                        int* __restrict__ ev, int n, int etot) {
  int i = blockIdx.x * NTHREADS + threadIdx.x;
  if (i < n) {
    int v = rp[i] + bsum[blockIdx.x];
    rp[i] = v;
    ev[v] = i;                 // self-loop: gathers hs[i] = dis[i]*h[i]
  }
  if (i == 0) rp[n] = etot;
}

// Atomic-free-global scatter (cols only; no val):
// slot = rp[r] + 1 (self slot) + prefix_over_blocks[b][r] + LDS-local counter.
__global__ __launch_bounds__(NTHREADS) void k_scatter3(
    const int* __restrict__ row, const int* __restrict__ col,
    const int* __restrict__ rp, const unsigned* __restrict__ prefR,
    int* __restrict__ ev, int e) {
  __shared__ unsigned lcur[NHW];
  int tid = threadIdx.x;
  for (int i = tid; i < NHW; i += NTHREADS) lcur[i] = 0;
  __syncthreads();
  int per = (e + CB - 1) / CB;
  int s = blockIdx.x * per;
  int en = min(e, s + per);
  const unsigned* pref = prefR + (size_t)blockIdx.x * NHW;
  for (int i = s + tid; i < en; i += NTHREADS) {
    int r = row[i], c = col[i];
    unsigned old = atomicAdd(&lcur[r >> 1], (r & 1) ? 0x10000u : 1u);
    unsigned loc = (r & 1) ? (old >> 16) : (old & 0xFFFFu);
    unsigned pw = pref[r >> 1];
    unsigned pb = (r & 1) ? (pw >> 16) : (pw & 0xFFFFu);
    ev[rp[r] + 1 + (int)pb + (int)loc] = c;
  }
}

// wT_bf16[l][f][k] = bf16(conv_w[l][k][f])  (transposed for MFMA B-fragments)
__global__ void k_wprime(const float* __restrict__ cw,
                         unsigned short* __restrict__ wTb) {
  int l = blockIdx.y;
  int idx = blockIdx.x * NTHREADS + threadIdx.x;   // 0..9215 = f*96 + k
  int f = idx / HID, k = idx % HID;
  wTb[l * HID * HID + idx] = f2bf(cw[l * HID * HID + k * HID + f]);
}

// ------ h0 = relu(x @ w0^T + b0): x0b = bf16(h0), hs0 = bf16(dis*h0) ---------
__global__ __launch_bounds__(NTHREADS) void k_lin0(
    const float* __restrict__ x, const float* __restrict__ w0,
    const float* __restrict__ b0, const float* __restrict__ dis,
    unsigned short* __restrict__ x0b, unsigned short* __restrict__ hs0, int n) {
  __shared__ float wl[INF * HID];   // wl[c][h], stride 96
  __shared__ float xT[INF * 68];    // xT[c][r], padded stride 68
  int tid = threadIdx.x;
#pragma unroll
  for (int i = 0; i < 6; ++i) {     // w0: 96x64 = 1536 float4
    int idx = tid + i * NTHREADS;
    int hrow = idx / 16, q = idx % 16;
    float4 v = *(const float4*)(w0 + hrow * INF + q * 4);
    wl[(q * 4 + 0) * HID + hrow] = v.x;
    wl[(q * 4 + 1) * HID + hrow] = v.y;
    wl[(q * 4 + 2) * HID + hrow] = v.z;
    wl[(q * 4 + 3) * HID + hrow] = v.w;
  }
  int r0 = blockIdx.x * 64;
#pragma unroll
  for (int i = 0; i < 4; ++i) {     // x tile: 64x64 = 1024 float4
    int idx = tid + i * NTHREADS;
    int r = idx / 16, q = idx % 16;
    int gr = r0 + r;
    float4 v = make_float4(0.f, 0.f, 0.f, 0.f);
    if (gr < n) v = *(const float4*)(x + (size_t)gr * INF + q * 4);
    xT[(q * 4 + 0) * 68 + r] = v.x;
    xT[(q * 4 + 1) * 68 + r] = v.y;
    xT[(q * 4 + 2) * 68 + r] = v.z;
    xT[(q * 4 + 3) * 68 + r] = v.w;
  }
  __syncthreads();
  int rg = tid & 15, cg = tid >> 4;
  float acc[4][6];
#pragma unroll
  for (int i = 0; i < 4; ++i)
#pragma unroll
    for (int j = 0; j < 6; ++j) acc[i][j] = 0.f;
#pragma unroll 4
  for (int k = 0; k < INF; ++k) {
    float4 s4 = *(const float4*)(xT + k * 68 + rg * 4);
    const float2* w2 = (const float2*)(wl + k * HID + cg * 6);
    float2 wa = w2[0], wb = w2[1], wc = w2[2];
    float wv[6] = {wa.x, wa.y, wb.x, wb.y, wc.x, wc.y};
    float sv[4] = {s4.x, s4.y, s4.z, s4.w};
#pragma unroll
    for (int i = 0; i < 4; ++i)
#pragma unroll
      for (int j = 0; j < 6; ++j) acc[i][j] = fmaf(sv[i], wv[j], acc[i][j]);
  }
  float bb[6];
#pragma unroll
  for (int j = 0; j < 6; ++j) bb[j] = b0[cg * 6 + j];
#pragma unroll
  for (int i = 0; i < 4; ++i) {
    int gr = r0 + rg * 4 + i;
    if (gr < n) {
      float r_[6];
#pragma unroll
      for (int j = 0; j < 6; ++j) r_[j] = fmaxf(acc[i][j] + bb[j], 0.f);
      float dr = dis[gr];
      unsigned* ob = (unsigned*)(x0b + (size_t)gr * HID + cg * 6);
      ob[0] = pack2bf(r_[0], r_[1]);
      ob[1] = pack2bf(r_[2], r_[3]);
      ob[2] = pack2bf(r_[4], r_[5]);
      unsigned* oh = (unsigned*)(hs0 + (size_t)gr * HID + cg * 6);
      oh[0] = pack2bf(dr * r_[0], dr * r_[1]);
      oh[1] = pack2bf(dr * r_[2], dr * r_[3]);
      oh[2] = pack2bf(dr * r_[4], dr * r_[5]);
    }
  }
}

// ---- fused layer: hs' = dis * relu((1-b)*s + b*(s @ w)),
//      s = 0.9*dis[r]*Σ hs[c] + 0.1*x0.
// R12 structure (best known: 32 rows/block, grid 1563). NEW: the 9 B-fragments
// (wT) are prefetched into registers at kernel entry — their L2 latency hides
// under the whole phase-1 gather instead of serializing into phase 2's MFMA
// chain. +36 VGPR -> ~90 total, under the (256,4) cap of 128 (no spill).
__global__ __launch_bounds__(NTHREADS, 4) void k_layer(
    const unsigned short* __restrict__ hs, const unsigned short* __restrict__ x0,
    const float* __restrict__ dis, const int* __restrict__ rp,
    const int* __restrict__ ev, const unsigned short* __restrict__ wT,
    unsigned short* __restrict__ hsout, float omb, float beta, int n) {
  __shared__ float red[8][4][100];          // 12.8 KB
  __shared__ unsigned short sT[32 * 104];   // 6.7 KB
  int tid = threadIdx.x;
  int hw = tid >> 5, lane = tid & 31;
  int eb = lane >> 2, fg = lane & 3;
  int r0 = blockIdx.x * 32;

  // ---- phase-2 geometry + B prefetch (issued before the gather loop) ----
  int lane64 = tid & 63, wave = tid >> 6;
  int l15 = lane64 & 15;     // A-row / B-col / C-col
  int kg = lane64 >> 4;      // k-group 0..3
  int rb = (wave & 1) * 16;  // row block
  int cb = (wave >> 1) * 48; // col block
  short8_t Breg[3][3];
#pragma unroll
  for (int kt = 0; kt < 3; ++kt)
#pragma unroll
    for (int ft = 0; ft < 3; ++ft)
      Breg[kt][ft] = *(const short8_t*)(wT + (cb + ft * 16 + l15) * HID +
                                        kt * 32 + kg * 8);

  // ---- phase 1: SpMM + residual into sT ----
  for (int sub = 0; sub < 4; ++sub) {
    int rl = sub * 8 + hw;
    int r = r0 + rl;
    if (r >= n) r = n - 1;          // duplicate work; store guarded in phase 2
    int e0 = rp[r], e1 = rp[r + 1]; // >= 1 edge (self-loop)
    float acc[24];
#pragma unroll
    for (int j = 0; j < 24; ++j) acc[j] = 0.f;
    int idx0 = e0 + eb;
    bool ok = idx0 < e1;
    idx0 = ok ? idx0 : e1 - 1;
    int cv = ev[idx0];
    for (int base = e0; base < e1; base += 8) {
      int cur = cv;
      bool okc = ok;
      int nb = base + 8;
      if (nb < e1) {                // prefetch next batch
        int i2 = nb + eb;
        ok = i2 < e1;
        i2 = ok ? i2 : e1 - 1;
        cv = ev[i2];
      }
      float v = okc ? 1.f : 0.f;    // lane mask (edge weight folded into hs)
      const unsigned short* hc = hs + (size_t)cur * HID + fg * 24;
      ushort8_t p0 = *(const ushort8_t*)(hc);
      ushort8_t p1 = *(const ushort8_t*)(hc + 8);
      ushort8_t p2 = *(const ushort8_t*)(hc + 16);
#pragma unroll
      for (int j = 0; j < 8; ++j) acc[j]      = fmaf(v, bf2f(p0[j]), acc[j]);
#pragma unroll
      for (int j = 0; j < 8; ++j) acc[8 + j]  = fmaf(v, bf2f(p1[j]), acc[8 + j]);
#pragma unroll
      for (int j = 0; j < 8; ++j) acc[16 + j] = fmaf(v, bf2f(p2[j]), acc[16 + j]);
    }
    // one butterfly step: pair edge-slots (eb, eb^1)
#pragma unroll
    for (int j = 0; j < 24; ++j) acc[j] += __shfl_xor(acc[j], 4);
    if ((eb & 1) == 0) {            // even-eb lanes hold pair sums -> 4 slots
      float* myr = &red[hw][eb >> 1][fg * 24];
#pragma unroll
      for (int j = 0; j < 6; ++j)
        *(float4*)(myr + j * 4) =
            make_float4(acc[j * 4], acc[j * 4 + 1], acc[j * 4 + 2], acc[j * 4 + 3]);
    }
    asm volatile("s_waitcnt lgkmcnt(0)" ::: "memory");
    __builtin_amdgcn_wave_barrier();
    if (lane < 24) {
      const float* base = &red[hw][0][lane * 4];
      float4 tot = *(const float4*)(base);
#pragma unroll
      for (int b = 1; b < 4; ++b) {
        float4 p = *(const float4*)(base + b * 100);
        tot.x += p.x; tot.y += p.y; tot.z += p.z; tot.w += p.w;
      }
      float w09 = 0.9f * dis[r];
      const unsigned* xr = (const unsigned*)(x0 + (size_t)r * HID + lane * 4);
      unsigned xa = xr[0], xb = xr[1];
      float s0 = w09 * tot.x + 0.1f * bf2f((unsigned short)(xa & 0xFFFFu));
      float s1 = w09 * tot.y + 0.1f * bf2f((unsigned short)(xa >> 16));
      float s2 = w09 * tot.z + 0.1f * bf2f((unsigned short)(xb & 0xFFFFu));
      float s3 = w09 * tot.w + 0.1f * bf2f((unsigned short)(xb >> 16));
      unsigned* op = (unsigned*)(sT + rl * 104 + lane * 4);
      op[0] = pack2bf(s0, s1);
      op[1] = pack2bf(s2, s3);
    }
    asm volatile("" ::: "memory");
    __builtin_amdgcn_wave_barrier();  // red reads done before next sub's writes
  }
  __syncthreads();
  // ---- phase 2: MFMA gemm; A = sT (LDS), B = Breg (prefetched) ----
  f32x4_t acc2[3];
#pragma unroll
  for (int i = 0; i < 3; ++i) acc2[i] = (f32x4_t)(0.f);
#pragma unroll
  for (int kt = 0; kt < 3; ++kt) {
    short8_t A = *(const short8_t*)(sT + (rb + l15) * 104 + kt * 32 + kg * 8);
#pragma unroll
    for (int ft = 0; ft < 3; ++ft)
      acc2[ft] = __builtin_amdgcn_mfma_f32_16x16x32_bf16(A, Breg[kt][ft], acc2[ft], 0, 0, 0);
  }
  // epilogue: C layout col = lane&15, row = (lane>>4)*4 + j   [m89-verified]
  float4 d4 = make_float4(0.f, 0.f, 0.f, 0.f);
  {
    int gr0 = r0 + rb + kg * 4;
    if (gr0 + 3 < n) d4 = *(const float4*)(dis + gr0);
    else {
      if (gr0 + 0 < n) d4.x = dis[gr0 + 0];
      if (gr0 + 1 < n) d4.y = dis[gr0 + 1];
      if (gr0 + 2 < n) d4.z = dis[gr0 + 2];
      if (gr0 + 3 < n) d4.w = dis[gr0 + 3];
    }
  }
  float dv[4] = {d4.x, d4.y, d4.z, d4.w};
#pragma unroll
  for (int ft = 0; ft < 3; ++ft) {
    int col = cb + ft * 16 + l15;
#pragma unroll
    for (int j = 0; j < 4; ++j) {
      int rl = rb + kg * 4 + j;
      int gr = r0 + rl;
      if (gr < n) {
        float sv = bf2f(sT[rl * 104 + col]);
        float o = fmaxf(omb * sv + beta * acc2[ft][j], 0.f);
        hsout[(size_t)gr * HID + col] = f2bf(dv[j] * o);
      }
    }
  }
}

// ------------- out = h @ w1^T + b1, h = rdis * hs (unscale on load) -----------
__global__ __launch_bounds__(NTHREADS) void k_lin1(
    const unsigned short* __restrict__ hs, const float* __restrict__ rdis,
    const float* __restrict__ w1, const float* __restrict__ b1,
    float* __restrict__ out, int n) {
  __shared__ float hT[HID * 68];    // [k][r]
  __shared__ float w1l[HID * OUTF]; // [k][o]
  int tid = threadIdx.x;
#pragma unroll
  for (int i = 0; i < 6; ++i) {     // w1: 16x96 = 1536 floats
    int idx = tid + i * NTHREADS;
    int o = idx / HID, k = idx % HID;
    w1l[k * OUTF + o] = w1[idx];
  }
  int r0 = blockIdx.x * 64;
#pragma unroll
  for (int i = 0; i < 3; ++i) {     // hs tile: 64x96 bf16 = 768 ushort8
    int idx = tid + i * NTHREADS;
    int r = idx / 12, q = idx % 12;
    int gr = r0 + r;
    ushort8_t v = (ushort8_t)0;
    float sc = 0.f;
    if (gr < n) {
      v = *(const ushort8_t*)(hs + (size_t)gr * HID + q * 8);
      sc = rdis[gr];
    }
#pragma unroll
    for (int j = 0; j < 8; ++j) hT[(q * 8 + j) * 68 + r] = sc * bf2f(v[j]);
  }
  __syncthreads();
  int r = tid & 63, og = tid >> 6;
  float acc[4] = {0.f, 0.f, 0.f, 0.f};
#pragma unroll 4
  for (int k = 0; k < HID; ++k) {
    float s = hT[k * 68 + r];
    float4 w4 = *(const float4*)(w1l + k * OUTF + og * 4);
    acc[0] = fmaf(s, w4.x, acc[0]);
    acc[1] = fmaf(s, w4.y, acc[1]);
    acc[2] = fmaf(s, w4.z, acc[2]);
    acc[3] = fmaf(s, w4.w, acc[3]);
  }
  int gr = r0 + r;
  if (gr < n) {
    float* op = out + (size_t)gr * OUTF + og * 4;
#pragma unroll
    for (int j = 0; j < 4; ++j) op[j] = acc[j] + b1[og * 4 + j];
  }
}

extern "C" void kernel_launch(void* const* d_in, const int* in_sizes, int n_in,
                              void* d_out, int out_size, void* d_ws, size_t ws_size,
                              hipStream_t stream) {
  const float* x  = (const float*)d_in[0];
  const int*   ei = (const int*)d_in[1];     // [2][E]: rows then cols
  const float* w0 = (const float*)d_in[2];
  const float* b0 = (const float*)d_in[3];
  const float* w1 = (const float*)d_in[4];
  const float* b1 = (const float*)d_in[5];
  const float* cw = (const float*)d_in[6];
  int n = in_sizes[0] / INF;    // 50000
  int e = in_sizes[1] / 2;      // 800000
  const int* row = ei;
  const int* col = ei + e;

  char* ws = (char*)d_ws;
  size_t off = 0;
  auto alloc = [&](size_t bytes) -> void* {
    void* p = (void*)(ws + off);
    off += (bytes + 255) & ~(size_t)255;
    return p;
  };
  unsigned short* x0b = (unsigned short*)alloc((size_t)n * HID * 2);
  unsigned short* hsA = (unsigned short*)alloc((size_t)n * HID * 2);
  unsigned short* hsB = (unsigned short*)alloc((size_t)n * HID * 2);
  unsigned short* wTb = (unsigned short*)alloc((size_t)NLAYERS * HID * HID * 2);
  float* dis  = (float*)alloc((size_t)n * 4);
  float* rdis = (float*)alloc((size_t)n * 4);
  int*   cnt  = (int*)alloc((size_t)n * 4);
  int*   rp   = (int*)alloc((size_t)(n + 1) * 4);
  int*   ev   = (int*)alloc((size_t)(e + n) * 4);   // + self-loop slots
  int*   bsum = (int*)alloc(1024 * 4);
  // partial histograms alias x0b/hsA/hsB (25.7 MB <= 28.8 MB; those buffers are
  // first written by k_lin0 / k_layer, which run after k_scatter3)
  unsigned* partR = (unsigned*)x0b;
  unsigned* partC = partR + (size_t)CB * NHW;
  int nw = (n + 1) / 2;         // packed words (<= NHW)
  (void)ws_size; (void)n_in; (void)out_size;

  int nb  = (n + NTHREADS - 1) / NTHREADS;   // 196
  int r64 = (n + 63) / 64;                   // 782
  int r32 = (n + 31) / 32;                   // 1563

  k_hist<<<CB, NTHREADS, 0, stream>>>(row, e, partR, nw);
  k_hist<<<CB, NTHREADS, 0, stream>>>(col, e, partC, nw);
  k_hmerge<<<(nw + NTHREADS - 1) / NTHREADS, NTHREADS, 0, stream>>>(
      partR, partC, cnt, dis, rdis, n, nw);
  k_scan1<<<nb, NTHREADS, 0, stream>>>(cnt, rp, bsum, n);
  k_scan2<<<1, NTHREADS, 0, stream>>>(bsum, nb);
  k_scan3<<<nb, NTHREADS, 0, stream>>>(rp, bsum, ev, n, e + n);
  k_scatter3<<<CB, NTHREADS, 0, stream>>>(row, col, rp, partR, ev, e);
  k_wprime<<<dim3(36, NLAYERS), NTHREADS, 0, stream>>>(cw, wTb);
  k_lin0<<<r64, NTHREADS, 0, stream>>>(x, w0, b0, dis, x0b, hsA, n);

  const unsigned short* hin = hsA;
  for (int l = 0; l < NLAYERS; ++l) {
    unsigned short* hout = (l & 1) ? hsA : hsB;
    float beta = logf(0.5f / (float)(l + 1) + 1.0f);
    k_layer<<<r32, NTHREADS, 0, stream>>>(hin, x0b, dis, rp, ev,
                                          wTb + (size_t)l * HID * HID, hout,
                                          1.0f - beta, beta, n);
    hin = hout;
  }
  k_lin1<<<r64, NTHREADS, 0, stream>>>(hin, rdis, w1, b1, (float*)d_out, n);
}

// Round 16
// 607.244 us; speedup vs baseline: 1.1253x; 1.1240x over previous
//
#include <hip/hip_runtime.h>

#define NTHREADS 256
#define HID 96
#define INF 64
#define OUTF 16
#define NLAYERS 16
#define NHW 25088     // packed histogram words (2 nodes/word), fits n<=50176
#define CB 128        // histogram/scatter blocks (per-block edges 6250 < 65536)

typedef __attribute__((ext_vector_type(8))) unsigned short ushort8_t;
typedef __attribute__((ext_vector_type(8))) short short8_t;   // MFMA bf16 A/B frag
typedef __attribute__((ext_vector_type(4))) float f32x4_t;    // MFMA C/D frag

static __device__ __forceinline__ float bf2f(unsigned short u) {
  return __uint_as_float(((unsigned)u) << 16);
}
static __device__ __forceinline__ unsigned short f2bf(float x) {
  unsigned u = __float_as_uint(x);
  return (unsigned short)((u + 0x7FFF + ((u >> 16) & 1)) >> 16);  // RNE
}
static __device__ __forceinline__ unsigned pack2bf(float a, float b) {
  return (unsigned)f2bf(a) | ((unsigned)f2bf(b) << 16);
}

// ---------------- preprocessing ----------------
// LDS-privatized histogram over idx[] (row or col), packed 2 nodes/u32 word.
__global__ __launch_bounds__(NTHREADS) void k_hist(
    const int* __restrict__ idx, int e, unsigned* __restrict__ part, int nw) {
  __shared__ unsigned hh[NHW];
  int tid = threadIdx.x;
  for (int i = tid; i < NHW; i += NTHREADS) hh[i] = 0;
  __syncthreads();
  int per = (e + CB - 1) / CB;
  int s = blockIdx.x * per;
  int en = min(e, s + per);
  for (int i = s + tid; i < en; i += NTHREADS) {
    int v = idx[i];
    atomicAdd(&hh[v >> 1], (v & 1) ? 0x10000u : 1u);
  }
  __syncthreads();
  unsigned* dst = part + (size_t)blockIdx.x * NHW;
  for (int i = tid; i < nw; i += NTHREADS) dst[i] = hh[i];
}

// Sum the CB partial histograms -> cnt (rows); degree over cols -> dis/rdis.
// Also rewrites partR in place as the EXCLUSIVE PREFIX over blocks (packed u16).
__global__ void k_hmerge(unsigned* __restrict__ partR,
                         const unsigned* __restrict__ partC,
                         int* __restrict__ cnt, float* __restrict__ dis,
                         float* __restrict__ rdis, int n, int nw) {
  int w = blockIdx.x * NTHREADS + threadIdx.x;
  if (w >= nw) return;
  unsigned rl = 0, rh = 0, cl = 0, ch = 0;
#pragma unroll 4
  for (int b = 0; b < CB; ++b) {
    size_t o = (size_t)b * NHW + w;
    unsigned pr = partR[o];
    partR[o] = rl | (rh << 16);          // exclusive prefix (fits u16)
    rl += pr & 0xFFFFu; rh += pr >> 16;
    unsigned pc = partC[o];
    cl += pc & 0xFFFFu; ch += pc >> 16;
  }
  int i0 = 2 * w, i1 = 2 * w + 1;
  if (i0 < n) {
    cnt[i0] = 1 + (int)rl;
    float d = (float)(1 + (int)cl);
    dis[i0] = rsqrtf(d); rdis[i0] = sqrtf(d);
  }
  if (i1 < n) {
    cnt[i1] = 1 + (int)rh;
    float d = (float)(1 + (int)ch);
    dis[i1] = rsqrtf(d); rdis[i1] = sqrtf(d);
  }
}

__global__ void k_scan1(const int* __restrict__ cnt, int* __restrict__ rp,
                        int* __restrict__ bsum, int n) {
  __shared__ int sh[NTHREADS];
  int t = threadIdx.x;
  int i = blockIdx.x * NTHREADS + t;
  int v = (i < n) ? cnt[i] : 0;
  sh[t] = v;
  __syncthreads();
  for (int ofs = 1; ofs < NTHREADS; ofs <<= 1) {
    int u = (t >= ofs) ? sh[t - ofs] : 0;
    __syncthreads();
    sh[t] += u;
    __syncthreads();
  }
  if (i < n) rp[i] = sh[t] - v;
  if (t == NTHREADS - 1) bsum[blockIdx.x] = sh[t];
}

__global__ void k_scan2(int* __restrict__ bsum, int nb) {  // nb <= 256
  __shared__ int sh[NTHREADS];
  int t = threadIdx.x;
  int v = (t < nb) ? bsum[t] : 0;
  sh[t] = v;
  __syncthreads();
  for (int ofs = 1; ofs < NTHREADS; ofs <<= 1) {
    int u = (t >= ofs) ? sh[t - ofs] : 0;
    __syncthreads();
    sh[t] += u;
    __syncthreads();
  }
  if (t < nb) bsum[t] = sh[t] - v;
}

// finalize rp AND write the self-loop edge into slot 0 of each row
__global__ void k_scan3(int* __restrict__ rp, const int* __restrict__ bsum,
                        int* __restrict__ ev, int n, int etot) {
  int i = blockIdx.x * NTHREADS + threadIdx.x;
  if (i < n) {
    int v = rp[i] + bsum[blockIdx.x];
    rp[i] = v;
    ev[v] = i;                 // self-loop: gathers hs[i] = dis[i]*h[i]
  }
  if (i == 0) rp[n] = etot;
}

// Atomic-free-global scatter (cols only; no val):
// slot = rp[r] + 1 (self slot) + prefix_over_blocks[b][r] + LDS-local counter.
__global__ __launch_bounds__(NTHREADS) void k_scatter3(
    const int* __restrict__ row, const int* __restrict__ col,
    const int* __restrict__ rp, const unsigned* __restrict__ prefR,
    int* __restrict__ ev, int e) {
  __shared__ unsigned lcur[NHW];
  int tid = threadIdx.x;
  for (int i = tid; i < NHW; i += NTHREADS) lcur[i] = 0;
  __syncthreads();
  int per = (e + CB - 1) / CB;
  int s = blockIdx.x * per;
  int en = min(e, s + per);
  const unsigned* pref = prefR + (size_t)blockIdx.x * NHW;
  for (int i = s + tid; i < en; i += NTHREADS) {
    int r = row[i], c = col[i];
    unsigned old = atomicAdd(&lcur[r >> 1], (r & 1) ? 0x10000u : 1u);
    unsigned loc = (r & 1) ? (old >> 16) : (old & 0xFFFFu);
    unsigned pw = pref[r >> 1];
    unsigned pb = (r & 1) ? (pw >> 16) : (pw & 0xFFFFu);
    ev[rp[r] + 1 + (int)pb + (int)loc] = c;
  }
}

// wT_bf16[l][f][k] = bf16(conv_w[l][k][f])  (transposed for MFMA B-fragments)
__global__ void k_wprime(const float* __restrict__ cw,
                         unsigned short* __restrict__ wTb) {
  int l = blockIdx.y;
  int idx = blockIdx.x * NTHREADS + threadIdx.x;   // 0..9215 = f*96 + k
  int f = idx / HID, k = idx % HID;
  wTb[l * HID * HID + idx] = f2bf(cw[l * HID * HID + k * HID + f]);
}

// ------ h0 = relu(x @ w0^T + b0): x0b = bf16(h0), hs0 = bf16(dis*h0) ---------
__global__ __launch_bounds__(NTHREADS) void k_lin0(
    const float* __restrict__ x, const float* __restrict__ w0,
    const float* __restrict__ b0, const float* __restrict__ dis,
    unsigned short* __restrict__ x0b, unsigned short* __restrict__ hs0, int n) {
  __shared__ float wl[INF * HID];   // wl[c][h], stride 96
  __shared__ float xT[INF * 68];    // xT[c][r], padded stride 68
  int tid = threadIdx.x;
#pragma unroll
  for (int i = 0; i < 6; ++i) {     // w0: 96x64 = 1536 float4
    int idx = tid + i * NTHREADS;
    int hrow = idx / 16, q = idx % 16;
    float4 v = *(const float4*)(w0 + hrow * INF + q * 4);
    wl[(q * 4 + 0) * HID + hrow] = v.x;
    wl[(q * 4 + 1) * HID + hrow] = v.y;
    wl[(q * 4 + 2) * HID + hrow] = v.z;
    wl[(q * 4 + 3) * HID + hrow] = v.w;
  }
  int r0 = blockIdx.x * 64;
#pragma unroll
  for (int i = 0; i < 4; ++i) {     // x tile: 64x64 = 1024 float4
    int idx = tid + i * NTHREADS;
    int r = idx / 16, q = idx % 16;
    int gr = r0 + r;
    float4 v = make_float4(0.f, 0.f, 0.f, 0.f);
    if (gr < n) v = *(const float4*)(x + (size_t)gr * INF + q * 4);
    xT[(q * 4 + 0) * 68 + r] = v.x;
    xT[(q * 4 + 1) * 68 + r] = v.y;
    xT[(q * 4 + 2) * 68 + r] = v.z;
    xT[(q * 4 + 3) * 68 + r] = v.w;
  }
  __syncthreads();
  int rg = tid & 15, cg = tid >> 4;
  float acc[4][6];
#pragma unroll
  for (int i = 0; i < 4; ++i)
#pragma unroll
    for (int j = 0; j < 6; ++j) acc[i][j] = 0.f;
#pragma unroll 4
  for (int k = 0; k < INF; ++k) {
    float4 s4 = *(const float4*)(xT + k * 68 + rg * 4);
    const float2* w2 = (const float2*)(wl + k * HID + cg * 6);
    float2 wa = w2[0], wb = w2[1], wc = w2[2];
    float wv[6] = {wa.x, wa.y, wb.x, wb.y, wc.x, wc.y};
    float sv[4] = {s4.x, s4.y, s4.z, s4.w};
#pragma unroll
    for (int i = 0; i < 4; ++i)
#pragma unroll
      for (int j = 0; j < 6; ++j) acc[i][j] = fmaf(sv[i], wv[j], acc[i][j]);
  }
  float bb[6];
#pragma unroll
  for (int j = 0; j < 6; ++j) bb[j] = b0[cg * 6 + j];
#pragma unroll
  for (int i = 0; i < 4; ++i) {
    int gr = r0 + rg * 4 + i;
    if (gr < n) {
      float r_[6];
#pragma unroll
      for (int j = 0; j < 6; ++j) r_[j] = fmaxf(acc[i][j] + bb[j], 0.f);
      float dr = dis[gr];
      unsigned* ob = (unsigned*)(x0b + (size_t)gr * HID + cg * 6);
      ob[0] = pack2bf(r_[0], r_[1]);
      ob[1] = pack2bf(r_[2], r_[3]);
      ob[2] = pack2bf(r_[4], r_[5]);
      unsigned* oh = (unsigned*)(hs0 + (size_t)gr * HID + cg * 6);
      oh[0] = pack2bf(dr * r_[0], dr * r_[1]);
      oh[1] = pack2bf(dr * r_[2], dr * r_[3]);
      oh[2] = pack2bf(dr * r_[4], dr * r_[5]);
    }
  }
}

// ---- fused layer: hs' = dis * relu((1-b)*s + b*(s @ w)),
//      s = 0.9*dis[r]*Σ hs[c] + 0.1*x0.
// R12 structure, byte-identical (best known 609 µs): 32 rows/block, grid 1563.
// Phase 1: half-wave per row, 4 subs; one shfl_xor step + LDS reduce over 4
// slots. Phase 2: 4 waves split 32x96 as 2x2; B from global wT (L2-resident).
// NOTE (R14 lesson): do NOT prefetch B into registers before phase 1 — the
// +36 held VGPRs (40->80) halve wave residency during the latency-bound
// gather and cost ~10%.
__global__ __launch_bounds__(NTHREADS, 4) void k_layer(
    const unsigned short* __restrict__ hs, const unsigned short* __restrict__ x0,
    const float* __restrict__ dis, const int* __restrict__ rp,
    const int* __restrict__ ev, const unsigned short* __restrict__ wT,
    unsigned short* __restrict__ hsout, float omb, float beta, int n) {
  __shared__ float red[8][4][100];          // 12.8 KB
  __shared__ unsigned short sT[32 * 104];   // 6.7 KB
  int tid = threadIdx.x;
  int hw = tid >> 5, lane = tid & 31;
  int eb = lane >> 2, fg = lane & 3;
  int r0 = blockIdx.x * 32;

  // ---- phase 1: SpMM + residual into sT ----
  for (int sub = 0; sub < 4; ++sub) {
    int rl = sub * 8 + hw;
    int r = r0 + rl;
    if (r >= n) r = n - 1;          // duplicate work; store guarded in phase 2
    int e0 = rp[r], e1 = rp[r + 1]; // >= 1 edge (self-loop)
    float acc[24];
#pragma unroll
    for (int j = 0; j < 24; ++j) acc[j] = 0.f;
    int idx0 = e0 + eb;
    bool ok = idx0 < e1;
    idx0 = ok ? idx0 : e1 - 1;
    int cv = ev[idx0];
    for (int base = e0; base < e1; base += 8) {
      int cur = cv;
      bool okc = ok;
      int nb = base + 8;
      if (nb < e1) {                // prefetch next batch
        int i2 = nb + eb;
        ok = i2 < e1;
        i2 = ok ? i2 : e1 - 1;
        cv = ev[i2];
      }
      float v = okc ? 1.f : 0.f;    // lane mask (edge weight folded into hs)
      const unsigned short* hc = hs + (size_t)cur * HID + fg * 24;
      ushort8_t p0 = *(const ushort8_t*)(hc);
      ushort8_t p1 = *(const ushort8_t*)(hc + 8);
      ushort8_t p2 = *(const ushort8_t*)(hc + 16);
#pragma unroll
      for (int j = 0; j < 8; ++j) acc[j]      = fmaf(v, bf2f(p0[j]), acc[j]);
#pragma unroll
      for (int j = 0; j < 8; ++j) acc[8 + j]  = fmaf(v, bf2f(p1[j]), acc[8 + j]);
#pragma unroll
      for (int j = 0; j < 8; ++j) acc[16 + j] = fmaf(v, bf2f(p2[j]), acc[16 + j]);
    }
    // one butterfly step: pair edge-slots (eb, eb^1)
#pragma unroll
    for (int j = 0; j < 24; ++j) acc[j] += __shfl_xor(acc[j], 4);
    if ((eb & 1) == 0) {            // even-eb lanes hold pair sums -> 4 slots
      float* myr = &red[hw][eb >> 1][fg * 24];
#pragma unroll
      for (int j = 0; j < 6; ++j)
        *(float4*)(myr + j * 4) =
            make_float4(acc[j * 4], acc[j * 4 + 1], acc[j * 4 + 2], acc[j * 4 + 3]);
    }
    asm volatile("s_waitcnt lgkmcnt(0)" ::: "memory");
    __builtin_amdgcn_wave_barrier();
    if (lane < 24) {
      const float* base = &red[hw][0][lane * 4];
      float4 tot = *(const float4*)(base);
#pragma unroll
      for (int b = 1; b < 4; ++b) {
        float4 p = *(const float4*)(base + b * 100);
        tot.x += p.x; tot.y += p.y; tot.z += p.z; tot.w += p.w;
      }
      float w09 = 0.9f * dis[r];
      const unsigned* xr = (const unsigned*)(x0 + (size_t)r * HID + lane * 4);
      unsigned xa = xr[0], xb = xr[1];
      float s0 = w09 * tot.x + 0.1f * bf2f((unsigned short)(xa & 0xFFFFu));
      float s1 = w09 * tot.y + 0.1f * bf2f((unsigned short)(xa >> 16));
      float s2 = w09 * tot.z + 0.1f * bf2f((unsigned short)(xb & 0xFFFFu));
      float s3 = w09 * tot.w + 0.1f * bf2f((unsigned short)(xb >> 16));
      unsigned* op = (unsigned*)(sT + rl * 104 + lane * 4);
      op[0] = pack2bf(s0, s1);
      op[1] = pack2bf(s2, s3);
    }
    asm volatile("" ::: "memory");
    __builtin_amdgcn_wave_barrier();  // red reads done before next sub's writes
  }
  __syncthreads();
  // ---- phase 2: MFMA gemm; 4 waves tile 32x96 as 2 rowblocks x 2 colblocks --
  int lane64 = tid & 63, wave = tid >> 6;
  int l15 = lane64 & 15;    // A-row / B-col / C-col
  int kg = lane64 >> 4;     // k-group 0..3
  int rb = (wave & 1) * 16; // row block
  int cb = (wave >> 1) * 48; // col block
  f32x4_t acc2[3];
#pragma unroll
  for (int i = 0; i < 3; ++i) acc2[i] = (f32x4_t)(0.f);
#pragma unroll
  for (int kt = 0; kt < 3; ++kt) {
    short8_t A = *(const short8_t*)(sT + (rb + l15) * 104 + kt * 32 + kg * 8);
#pragma unroll
    for (int ft = 0; ft < 3; ++ft) {
      short8_t B = *(const short8_t*)(wT + (cb + ft * 16 + l15) * HID + kt * 32 + kg * 8);
      acc2[ft] = __builtin_amdgcn_mfma_f32_16x16x32_bf16(A, B, acc2[ft], 0, 0, 0);
    }
  }
  // epilogue: C layout col = lane&15, row = (lane>>4)*4 + j   [m89-verified]
#pragma unroll
  for (int ft = 0; ft < 3; ++ft) {
    int col = cb + ft * 16 + l15;
#pragma unroll
    for (int j = 0; j < 4; ++j) {
      int rl = rb + kg * 4 + j;
      int gr = r0 + rl;
      if (gr < n) {
        float sv = bf2f(sT[rl * 104 + col]);
        float o = fmaxf(omb * sv + beta * acc2[ft][j], 0.f);
        hsout[(size_t)gr * HID + col] = f2bf(dis[gr] * o);
      }
    }
  }
}

// ------------- out = h @ w1^T + b1, h = rdis * hs (unscale on load) -----------
__global__ __launch_bounds__(NTHREADS) void k_lin1(
    const unsigned short* __restrict__ hs, const float* __restrict__ rdis,
    const float* __restrict__ w1, const float* __restrict__ b1,
    float* __restrict__ out, int n) {
  __shared__ float hT[HID * 68];    // [k][r]
  __shared__ float w1l[HID * OUTF]; // [k][o]
  int tid = threadIdx.x;
#pragma unroll
  for (int i = 0; i < 6; ++i) {     // w1: 16x96 = 1536 floats
    int idx = tid + i * NTHREADS;
    int o = idx / HID, k = idx % HID;
    w1l[k * OUTF + o] = w1[idx];
  }
  int r0 = blockIdx.x * 64;
#pragma unroll
  for (int i = 0; i < 3; ++i) {     // hs tile: 64x96 bf16 = 768 ushort8
    int idx = tid + i * NTHREADS;
    int r = idx / 12, q = idx % 12;
    int gr = r0 + r;
    ushort8_t v = (ushort8_t)0;
    float sc = 0.f;
    if (gr < n) {
      v = *(const ushort8_t*)(hs + (size_t)gr * HID + q * 8);
      sc = rdis[gr];
    }
#pragma unroll
    for (int j = 0; j < 8; ++j) hT[(q * 8 + j) * 68 + r] = sc * bf2f(v[j]);
  }
  __syncthreads();
  int r = tid & 63, og = tid >> 6;
  float acc[4] = {0.f, 0.f, 0.f, 0.f};
#pragma unroll 4
  for (int k = 0; k < HID; ++k) {
    float s = hT[k * 68 + r];
    float4 w4 = *(const float4*)(w1l + k * OUTF + og * 4);
    acc[0] = fmaf(s, w4.x, acc[0]);
    acc[1] = fmaf(s, w4.y, acc[1]);
    acc[2] = fmaf(s, w4.z, acc[2]);
    acc[3] = fmaf(s, w4.w, acc[3]);
  }
  int gr = r0 + r;
  if (gr < n) {
    float* op = out + (size_t)gr * OUTF + og * 4;
#pragma unroll
    for (int j = 0; j < 4; ++j) op[j] = acc[j] + b1[og * 4 + j];
  }
}

extern "C" void kernel_launch(void* const* d_in, const int* in_sizes, int n_in,
                              void* d_out, int out_size, void* d_ws, size_t ws_size,
                              hipStream_t stream) {
  const float* x  = (const float*)d_in[0];
  const int*   ei = (const int*)d_in[1];     // [2][E]: rows then cols
  const float* w0 = (const float*)d_in[2];
  const float* b0 = (const float*)d_in[3];
  const float* w1 = (const float*)d_in[4];
  const float* b1 = (const float*)d_in[5];
  const float* cw = (const float*)d_in[6];
  int n = in_sizes[0] / INF;    // 50000
  int e = in_sizes[1] / 2;      // 800000
  const int* row = ei;
  const int* col = ei + e;

  char* ws = (char*)d_ws;
  size_t off = 0;
  auto alloc = [&](size_t bytes) -> void* {
    void* p = (void*)(ws + off);
    off += (bytes + 255) & ~(size_t)255;
    return p;
  };
  unsigned short* x0b = (unsigned short*)alloc((size_t)n * HID * 2);
  unsigned short* hsA = (unsigned short*)alloc((size_t)n * HID * 2);
  unsigned short* hsB = (unsigned short*)alloc((size_t)n * HID * 2);
  unsigned short* wTb = (unsigned short*)alloc((size_t)NLAYERS * HID * HID * 2);
  float* dis  = (float*)alloc((size_t)n * 4);
  float* rdis = (float*)alloc((size_t)n * 4);
  int*   cnt  = (int*)alloc((size_t)n * 4);
  int*   rp   = (int*)alloc((size_t)(n + 1) * 4);
  int*   ev   = (int*)alloc((size_t)(e + n) * 4);   // + self-loop slots
  int*   bsum = (int*)alloc(1024 * 4);
  // partial histograms alias x0b/hsA/hsB (25.7 MB <= 28.8 MB; those buffers are
  // first written by k_lin0 / k_layer, which run after k_scatter3)
  unsigned* partR = (unsigned*)x0b;
  unsigned* partC = partR + (size_t)CB * NHW;
  int nw = (n + 1) / 2;         // packed words (<= NHW)
  (void)ws_size; (void)n_in; (void)out_size;

  int nb  = (n + NTHREADS - 1) / NTHREADS;   // 196
  int r64 = (n + 63) / 64;                   // 782
  int r32 = (n + 31) / 32;                   // 1563

  k_hist<<<CB, NTHREADS, 0, stream>>>(row, e, partR, nw);
  k_hist<<<CB, NTHREADS, 0, stream>>>(col, e, partC, nw);
  k_hmerge<<<(nw + NTHREADS - 1) / NTHREADS, NTHREADS, 0, stream>>>(
      partR, partC, cnt, dis, rdis, n, nw);
  k_scan1<<<nb, NTHREADS, 0, stream>>>(cnt, rp, bsum, n);
  k_scan2<<<1, NTHREADS, 0, stream>>>(bsum, nb);
  k_scan3<<<nb, NTHREADS, 0, stream>>>(rp, bsum, ev, n, e + n);
  k_scatter3<<<CB, NTHREADS, 0, stream>>>(row, col, rp, partR, ev, e);
  k_wprime<<<dim3(36, NLAYERS), NTHREADS, 0, stream>>>(cw, wTb);
  k_lin0<<<r64, NTHREADS, 0, stream>>>(x, w0, b0, dis, x0b, hsA, n);

  const unsigned short* hin = hsA;
  for (int l = 0; l < NLAYERS; ++l) {
    unsigned short* hout = (l & 1) ? hsA : hsB;
    float beta = logf(0.5f / (float)(l + 1) + 1.0f);
    k_layer<<<r32, NTHREADS, 0, stream>>>(hin, x0b, dis, rp, ev,
                                          wTb + (size_t)l * HID * HID, hout,
                                          1.0f - beta, beta, n);
    hin = hout;
  }
  k_lin1<<<r64, NTHREADS, 0, stream>>>(hin, rdis, w1, b1, (float*)d_out, n);
}